// Round 25
// baseline (118.844 us; speedup 1.0000x reference)
//
#include <hip/hip_runtime.h>

#define B_    2
#define S_    1024
#define NH_   32
#define NKV_  8
#define T_    (B_*S_)

typedef unsigned short u16;
typedef unsigned int u32;
typedef __attribute__((ext_vector_type(8))) short bf16x8;
typedef __attribute__((ext_vector_type(4))) float f32x4;

__device__ __forceinline__ float bf2f(u16 u) {
    union { float f; unsigned int i; } c; c.i = ((unsigned int)u) << 16; return c.f;
}
// pack two f32 -> 2xbf16 (lo in low16), RNE
__device__ __forceinline__ u32 cvtpk(float lo, float hi) {
    u32 r;
    asm("v_cvt_pk_bf16_f32 %0, %1, %2" : "=v"(r) : "v"(lo), "v"(hi));
    return r;
}
// single f32 -> bf16 via cvt_pk (1 VALU op, RNE)
__device__ __forceinline__ u16 f2bf(float f) {
    return (u16)cvtpk(f, 0.f);
}

// async global->LDS, 16B per lane; LDS dest = wave-uniform base + lane*16 (linear)
__device__ __forceinline__ void gld_lds16(const void* g, void* s) {
    __builtin_amdgcn_global_load_lds(
        (const __attribute__((address_space(1))) void*)g,
        (__attribute__((address_space(3))) void*)s,
        16, 0, 0);
}

// ------------------------------------------------------------------
// preproc1: [0,2048) hidden f32->bf16; [2048,3584) wqkv pack-transpose;
//           [3584,4608) wo transpose -> woT bf16 [2048][2048]
// Transpose path vectorized (G13): float4 reads, uint2 bf16 stores.
// ------------------------------------------------------------------
__global__ __launch_bounds__(256) void preproc1(
    const float* __restrict__ hidden, const float* __restrict__ wq,
    const float* __restrict__ wk, const float* __restrict__ wv,
    const float* __restrict__ wo,
    u16* __restrict__ hidden_bf, u16* __restrict__ wqkvT, u16* __restrict__ woT)
{
    __shared__ float t[64][65];
    const int bid = blockIdx.x, tid = threadIdx.x;
    if (bid < 2048) {
        int i = (bid * 256 + tid) * 8;
        float4 v0 = *reinterpret_cast<const float4*>(&hidden[i]);
        float4 v1 = *reinterpret_cast<const float4*>(&hidden[i + 4]);
        u32 ow[4] = { cvtpk(v0.x, v0.y), cvtpk(v0.z, v0.w),
                      cvtpk(v1.x, v1.y), cvtpk(v1.z, v1.w) };
        *reinterpret_cast<uint4*>(&hidden_bf[i]) = *reinterpret_cast<uint4*>(ow);
        return;
    }
    const float* src; int scol, sN, n0, k0;
    u16* dst; int dK;
    if (bid < 3584) {
        const int tt = bid - 2048;
        n0 = (tt % 48) * 64; k0 = (tt / 48) * 64;
        if (n0 < 2048)      { src = wq; scol = n0;        sN = 2048; }
        else if (n0 < 2560) { src = wk; scol = n0 - 2048; sN = 512;  }
        else                { src = wv; scol = n0 - 2560; sN = 512;  }
        dst = wqkvT; dK = 2048;
    } else {
        const int tt = bid - 3584;
        n0 = (tt % 32) * 64; k0 = (tt / 32) * 64;
        src = wo; scol = n0; sN = 2048;
        dst = woT; dK = 2048;
    }
    #pragma unroll
    for (int i = 0; i < 4; ++i) {
        int e = i * 256 + tid, r = e >> 4, c4 = (e & 15) * 4;
        float4 v = *reinterpret_cast<const float4*>(
            &src[(size_t)(k0 + r) * sN + scol + c4]);
        t[r][c4 + 0] = v.x;
        t[r][c4 + 1] = v.y;
        t[r][c4 + 2] = v.z;
        t[r][c4 + 3] = v.w;
    }
    __syncthreads();
    #pragma unroll
    for (int i = 0; i < 4; ++i) {
        int e = i * 256 + tid, rr = e >> 4, cc4 = (e & 15) * 4;
        u32 ow[2] = { cvtpk(t[cc4][rr], t[cc4 + 1][rr]),
                      cvtpk(t[cc4 + 2][rr], t[cc4 + 3][rr]) };
        *reinterpret_cast<uint2*>(&dst[(size_t)(n0 + rr) * dK + k0 + cc4])
            = *reinterpret_cast<uint2*>(ow);
    }
}

// ------------------------------------------------------------------
// bf16 MFMA GEMM, B^T input. C[M,N] = A[M,K] @ Bt[N,K]^T
// BM x BN tile (templated), BK=64, 4 waves (2x2), wave-tile
// (BM/2)x(BN/2), T2 XOR-swizzled LDS, double-buffered counted-vmcnt
// staging. XCD mapping: each XCD owns MB/8 contiguous m-panels and
// ALL n-columns (grid/8 blocks per XCD are exactly co-resident).
// ------------------------------------------------------------------
template<int BM, int BN, bool OUT_BF16>
__global__ __launch_bounds__(256) void gemm_bt(
    const u16* __restrict__ A, const u16* __restrict__ Bt,
    void* __restrict__ Cv, int M, int N, int K)
{
    constexpr int FM  = BM / 32;        // A frags per wave
    constexpr int FN  = BN / 32;        // B frags per wave
    constexpr int ACH = BM / 32;        // A chunks staged per wave
    constexpr int BCH = BN / 32;        // B chunks staged per wave
    __shared__ u16 As[2][BM * 64];
    __shared__ u16 Bs[2][BN * 64];
    const int MB = M / BM;
    const int mpx = MB >> 3;                          // m-panels per XCD
    const int xcd = blockIdx.x & 7, lid = blockIdx.x >> 3;
    const int bm = (xcd * mpx + (lid % mpx)) * BM;
    const int bn = (lid / mpx) * BN;
    const int tid = threadIdx.x;
    const int w = tid >> 6, lane = tid & 63;
    const int wr = w >> 1, wc = w & 1;
    const int l15 = lane & 15, lg = lane >> 4;
    const int srow = lane >> 3;                       // 0..7
    const int scolsw = (lane & 7) ^ srow;             // swizzled source 16B-chunk

    f32x4 acc[FM][FN] = {};
    const int nk = K >> 6;

#define GSTAGE(ks, bb) do {                                                    \
    const int kofs = (ks) * 64;                                                \
    _Pragma("unroll")                                                          \
    for (int i_ = 0; i_ < ACH; ++i_) {                                         \
        int chunk_ = w * ACH + i_;                                             \
        int row_ = chunk_ * 8 + srow;                                          \
        gld_lds16(&A[(size_t)(bm + row_) * K + kofs + scolsw * 8],             \
                  &As[bb][chunk_ * 512]);                                      \
    }                                                                          \
    _Pragma("unroll")                                                          \
    for (int j_ = 0; j_ < BCH; ++j_) {                                         \
        int chunk_ = w * BCH + j_;                                             \
        int row_ = chunk_ * 8 + srow;                                          \
        gld_lds16(&Bt[(size_t)(bn + row_) * K + kofs + scolsw * 8],            \
                  &Bs[bb][chunk_ * 512]);                                      \
    } } while (0)

    GSTAGE(0, 0);
    for (int ks = 0; ks < nk; ++ks) {
        const int cur = ks & 1;
        if (ks + 1 < nk) {
            GSTAGE(ks + 1, cur ^ 1);
            if (ACH + BCH == 6)      { asm volatile("s_waitcnt vmcnt(6)" ::: "memory"); }
            else if (ACH + BCH == 4) { asm volatile("s_waitcnt vmcnt(4)" ::: "memory"); }
            else                     { asm volatile("s_waitcnt vmcnt(0)" ::: "memory"); }
        } else {
            asm volatile("s_waitcnt vmcnt(0)" ::: "memory");
        }
        __builtin_amdgcn_s_barrier();
        __builtin_amdgcn_sched_barrier(0);   // keep ds_reads below barrier

        #pragma unroll
        for (int kk = 0; kk < 2; ++kk) {
            const int phys = ((kk * 4 + lg) ^ (l15 & 7)) * 8;
            bf16x8 a[FM], b[FN];
            #pragma unroll
            for (int m = 0; m < FM; ++m)
                a[m] = *reinterpret_cast<const bf16x8*>(
                    &As[cur][(wr * (BM / 2) + m * 16 + l15) * 64 + phys]);
            #pragma unroll
            for (int n = 0; n < FN; ++n)
                b[n] = *reinterpret_cast<const bf16x8*>(
                    &Bs[cur][(wc * (BN / 2) + n * 16 + l15) * 64 + phys]);
            #pragma unroll
            for (int m = 0; m < FM; ++m)
                #pragma unroll
                for (int n = 0; n < FN; ++n)
                    acc[m][n] = __builtin_amdgcn_mfma_f32_16x16x32_bf16(
                        a[m], b[n], acc[m][n], 0, 0, 0);
        }
        __builtin_amdgcn_s_barrier();   // protect buffer reuse next iter
    }
#undef GSTAGE

    const int orow0 = bm + wr * (BM / 2), ocol0 = bn + wc * (BN / 2);
    #pragma unroll
    for (int m = 0; m < FM; ++m)
        #pragma unroll
        for (int n = 0; n < FN; ++n)
            #pragma unroll
            for (int r = 0; r < 4; ++r) {
                int row = orow0 + m * 16 + lg * 4 + r;
                int col = ocol0 + n * 16 + l15;
                float v = acc[m][n][r];
                if (OUT_BF16)
                    ((u16*)Cv)[(size_t)row * N + col] = f2bf(v);
                else
                    ((float*)Cv)[(size_t)row * N + col] = v;
            }
}

// ------------------------------------------------------------------
// Merged RMSNorm+RoPE (blocks [0,2048), token per block) and
// V transpose (blocks [2048,2304)) -> vT [(b*8+kvh)*64+d][1024]
// Q rows are additionally scaled by SC = 0.125*log2(e) so the attn
// kernel's softmax can use exp2 on the raw QK^T product directly.
// ------------------------------------------------------------------
template<int DIM>
__device__ __forceinline__ void rms_rope_row(
    u16* base, const float* __restrict__ w,
    const float* __restrict__ cs, const float* __restrict__ sn,
    float* row, float* red, int tid, float osc)
{
    float ss = 0.f;
    for (int i0 = tid * 8; i0 < DIM; i0 += 2048) {
        uint4 u = *reinterpret_cast<const uint4*>(&base[i0]);
        const u16* us = reinterpret_cast<const u16*>(&u);
        #pragma unroll
        for (int j = 0; j < 8; ++j) { float f = bf2f(us[j]); row[i0 + j] = f; ss += f * f; }
    }
    #pragma unroll
    for (int off = 1; off < 64; off <<= 1) ss += __shfl_xor(ss, off);
    if ((tid & 63) == 0) red[tid >> 6] = ss;
    __syncthreads();
    const float rstd = rsqrtf((red[0] + red[1] + red[2] + red[3]) * (1.0f / DIM) + 1e-6f);

    for (int i0 = tid * 8; i0 < DIM; i0 += 2048) {
        float ov[8];
        #pragma unroll
        for (int j = 0; j < 8; ++j) {
            int i = i0 + j, dh = i & 63, bb = i & ~63;
            int oi = (dh < 32) ? bb + dh + 32 : bb + dh - 32;
            float y     = row[i]  * rstd * w[i];
            float other = row[oi] * rstd * w[oi];
            if (dh < 32) other = -other;
            ov[j] = (y * cs[dh] + other * sn[dh]) * osc;
        }
        u32 ow[4] = { cvtpk(ov[0], ov[1]), cvtpk(ov[2], ov[3]),
                      cvtpk(ov[4], ov[5]), cvtpk(ov[6], ov[7]) };
        *reinterpret_cast<uint4*>(&base[i0]) = *reinterpret_cast<uint4*>(ow);
    }
}

__global__ __launch_bounds__(256) void rmsnorm_rope_vt(
    u16* __restrict__ x, const float* __restrict__ qnw, const float* __restrict__ knw,
    const float* __restrict__ cosb, const float* __restrict__ sinb,
    u16* __restrict__ vT)
{
    __shared__ float smem[2304];          // 9216 B, aliased
    const int bid = blockIdx.x, tid = threadIdx.x;
    if (bid < 2048) {
        const int t = bid;
        float* row = smem;
        float* red = smem + 2048;
        const float* cs = cosb + (size_t)t * 64;
        const float* sn = sinb + (size_t)t * 64;
        // Q: scaled by 0.125*log2(e) (softmax scale folded in)
        rms_rope_row<2048>(x + (size_t)t * 3072,        qnw, cs, sn, row, red, tid,
                           0.18033688f);
        __syncthreads();
        rms_rope_row<512 >(x + (size_t)t * 3072 + 2048, knw, cs, sn, row, red, tid,
                           1.0f);
        return;
    }
    // V transpose
    u16 (*tu)[72] = reinterpret_cast<u16(*)[72]>(smem);
    const int bid2 = bid - 2048;
    const int hd = bid2 % 16;              // b*8 + kvh
    const int s0 = (bid2 / 16) * 64;
    const int b = hd >> 3, kvh = hd & 7;
    #pragma unroll
    for (int i = 0; i < 2; ++i) {
        int chunk = i * 256 + tid;
        int r = chunk >> 3, c8 = (chunk & 7) * 8;
        uint4 u = *reinterpret_cast<const uint4*>(
            &x[(size_t)(b * 1024 + s0 + r) * 3072 + 2560 + kvh * 64 + c8]);
        *reinterpret_cast<uint4*>(&tu[r][c8]) = u;
    }
    __syncthreads();
    #pragma unroll
    for (int i = 0; i < 2; ++i) {
        int chunk = i * 256 + tid;
        int d = chunk >> 3, c8 = (chunk & 7) * 8;
        u16 o[8];
        #pragma unroll
        for (int j = 0; j < 8; ++j) o[j] = tu[c8 + j][d];
        *reinterpret_cast<uint4*>(&vT[((size_t)(hd * 64 + d)) * 1024 + s0 + c8])
            = *reinterpret_cast<uint4*>(o);
    }
}

// ------------------------------------------------------------------
// MFMA flash attention v15 = r7's 4-blocks/CU GEOMETRY x r24's LEAN
// step body. Block = 2 waves = pairs of 32-row strips (p, 31-p),
// uniform 17 tile-steps; grid 1024 XCD-chunked; K/V double-buffered
// (36KB LDS -> 4 blocks/CU, double the co-resident pipelines of the
// grid-512 config). Lean body: max-free softmax (scale pre-folded in
// Q), diagonal-only masking, cvt_pk packing, compiler-managed Ps RAW,
// single load-bearing sched_barrier. Counted vmcnt(8) (8 loads/wave
// per stage).
// ------------------------------------------------------------------
__global__ __launch_bounds__(128) void attn_pair(
    const u16* __restrict__ qkv,  // [2048][3072]
    const u16* __restrict__ vT,   // [16*64][1024]
    u16* __restrict__ ob)         // [2048][2048]
{
    __shared__ u16 Ks[2][64 * 64];
    __shared__ u16 Vs[2][64 * 64];
    __shared__ u16 Ps[2][16 * 64];

    const int bid = blockIdx.x;
    const int L   = (bid & 7) * 128 + (bid >> 3); // XCD-chunked, bijective
    const int g5  = L >> 6;                       // b*8 + kvh
    const int rem = L & 63;
    const int ha  = rem & 3;
    const int p   = rem >> 2;                     // pair index 0..15
    const int b = g5 >> 3, kvh = g5 & 7;
    const int h = kvh * 4 + ha;
    const int spA = p, spB = 31 - p;              // 32-row strip indices
    const int tilesA = (p >> 1) + 1;              // KV tiles for strip A

    const int tid = threadIdx.x, w = tid >> 6, lane = tid & 63;
    const int l15 = lane & 15, lg = lane >> 4;
    const int srow = lane >> 3;
    const int scolsw = (lane & 7) ^ srow;

    // Q fragments for both strips (wave w owns rows strip*32 + w*16 + l15)
    bf16x8 qfA[2], qfB[2];
    {
        const size_t rA = (size_t)(b * 1024 + spA * 32 + w * 16 + l15);
        const size_t rB = (size_t)(b * 1024 + spB * 32 + w * 16 + l15);
        #pragma unroll
        for (int kk = 0; kk < 2; ++kk) {
            qfA[kk] = *reinterpret_cast<const bf16x8*>(
                &qkv[rA * 3072 + h * 64 + kk * 32 + lg * 8]);
            qfB[kk] = *reinterpret_cast<const bf16x8*>(
                &qkv[rB * 3072 + h * 64 + kk * 32 + lg * 8]);
        }
    }
    asm volatile("s_waitcnt vmcnt(0)" ::: "memory");  // clean vmcnt for pipeline

    float lrA = 0.f, lrB = 0.f;          // per-lane partial row sums
    f32x4 oaccA[4] = {}, oaccB[4] = {};

    const u16* kbase = qkv + 2048 + kvh * 64;
    const u16* vbase = vT + (size_t)(g5 * 64) * 1024;
    const int qgA = spA * 32 + w * 16 + l15;
    const int qgB = spB * 32 + w * 16 + l15;

// 2 waves stage 64x64 K + 64x64 V: 8 chunks each of 8 rows; wave w does 4.
#define ASTAGE(kt, bb) do {                                                    \
    _Pragma("unroll")                                                          \
    for (int i_ = 0; i_ < 4; ++i_) {                                           \
        int chunk_ = w * 4 + i_;                                               \
        int row_ = chunk_ * 8 + srow;                                          \
        gld_lds16(&kbase[(size_t)(b * 1024 + (kt) * 64 + row_) * 3072          \
                         + scolsw * 8], &Ks[bb][chunk_ * 512]);                \
        gld_lds16(&vbase[(size_t)row_ * 1024 + (kt) * 64 + scolsw * 8],        \
                  &Vs[bb][chunk_ * 512]);                                      \
    } } while (0)

    // one tile-step: max-free online accumulation; scale pre-folded in Q.
    auto step = [&](int kt, int cur, const bf16x8 (&qf)[2],
                    float& lr, f32x4 (&oacc)[4], int qg, bool dz) {
        // swapped QK^T: D[key][q], lane holds q=l15, keys m*16+lg*4+r
        f32x4 sacc[4] = {};
        #pragma unroll
        for (int kk = 0; kk < 2; ++kk) {
            const int phys = ((kk * 4 + lg) ^ (l15 & 7)) * 8;
            #pragma unroll
            for (int m = 0; m < 4; ++m) {
                bf16x8 kf = *reinterpret_cast<const bf16x8*>(
                    &Ks[cur][(m * 16 + l15) * 64 + phys]);
                sacc[m] = __builtin_amdgcn_mfma_f32_16x16x32_bf16(
                    kf, qf[kk], sacc[m], 0, 0, 0);
            }
        }

        // max-free: P = exp2(S); mask only on the diagonal step
        float pv[4][4];
        if (dz) {
            #pragma unroll
            for (int m = 0; m < 4; ++m)
                #pragma unroll
                for (int r = 0; r < 4; ++r) {
                    float v = sacc[m][r];
                    if (kt * 64 + m * 16 + lg * 4 + r > qg) v = -1e30f;
                    pv[m][r] = exp2f(v);
                }
        } else {
            #pragma unroll
            for (int m = 0; m < 4; ++m)
                #pragma unroll
                for (int r = 0; r < 4; ++r)
                    pv[m][r] = exp2f(sacc[m][r]);
        }
        float ls = 0.f;
        #pragma unroll
        for (int m = 0; m < 4; ++m) {
            ls += (pv[m][0] + pv[m][1]) + (pv[m][2] + pv[m][3]);
            u32 pkw[2] = { cvtpk(pv[m][0], pv[m][1]),
                           cvtpk(pv[m][2], pv[m][3]) };
            const int keyc = m * 16 + lg * 4;
            const int phys = (keyc >> 3) ^ (l15 & 7);
            *reinterpret_cast<uint2*>(&Ps[w][l15 * 64 + phys * 8 + (keyc & 7)])
                = *reinterpret_cast<const uint2*>(pkw);
        }
        lr += ls;                         // per-lane partial; reduce at end

        // PV: O[q][d] += P[q][key] * V[key][d]
        // (Ps RAW handled by compiler's counted lgkm waits)
        #pragma unroll
        for (int kk = 0; kk < 2; ++kk) {
            const int phys = ((kk * 4 + lg) ^ (l15 & 7)) * 8;
            bf16x8 pf = *reinterpret_cast<const bf16x8*>(
                &Ps[w][l15 * 64 + phys]);
            #pragma unroll
            for (int d = 0; d < 4; ++d) {
                bf16x8 vf = *reinterpret_cast<const bf16x8*>(
                    &Vs[cur][(d * 16 + l15) * 64 + phys]);
                oacc[d] = __builtin_amdgcn_mfma_f32_16x16x32_bf16(
                    pf, vf, oacc[d], 0, 0, 0);
            }
        }
    };

    // unified 17-step schedule: s < tilesA -> strip A (kt=s), else B
    ASTAGE(0, 0);
    for (int s = 0; s <= 16; ++s) {
        const int cur = s & 1;
        if (s < 16) {
            const int sn = s + 1;
            const int ktn = (sn < tilesA) ? sn : (sn - tilesA);
            ASTAGE(ktn, cur ^ 1);
            asm volatile("s_waitcnt vmcnt(8)" ::: "memory");
        } else {
            asm volatile("s_waitcnt vmcnt(0)" ::: "memory");
        }
        __builtin_amdgcn_s_barrier();
        __builtin_amdgcn_sched_barrier(0);   // keep ds_reads below barrier

        if (s < tilesA)
            step(s,          cur, qfA, lrA, oaccA, qgA, s == tilesA - 1);
        else
            step(s - tilesA, cur, qfB, lrB, oaccB, qgB, s == 16);

        __builtin_amdgcn_s_barrier();    // all reads of cur done before reuse
    }
#undef ASTAGE

    // epilogues: reduce l across the 4 lane-groups once, then normalize.
    #pragma unroll
    for (int tt = 0; tt < 2; ++tt) {
        const int sp = tt ? spB : spA;
        float lsum = tt ? lrB : lrA;
        lsum += __shfl_xor(lsum, 16);
        lsum += __shfl_xor(lsum, 32);
        f32x4* oacc = tt ? oaccB : oaccA;
        float linv[4];
        #pragma unroll
        for (int r = 0; r < 4; ++r) {
            float lv = __shfl(lsum, (lane & 48) + ((lane >> 4) & 3) * 4 + r);
            linv[r] = 1.f / lv;
        }
        #pragma unroll
        for (int d = 0; d < 4; ++d)
            #pragma unroll
            for (int r = 0; r < 4; ++r)
                ob[(size_t)(b * 1024 + sp * 32 + w * 16 + lg * 4 + r) * 2048
                   + h * 64 + d * 16 + l15] = f2bf(oacc[d][r] * linv[r]);
    }
}

// ------------------------------------------------------------------
extern "C" void kernel_launch(void* const* d_in, const int* in_sizes, int n_in,
                              void* d_out, int out_size, void* d_ws, size_t ws_size,
                              hipStream_t stream)
{
    const float* hidden = (const float*)d_in[0];
    const float* cosb   = (const float*)d_in[1];
    const float* sinb   = (const float*)d_in[2];
    // d_in[3] = attention_mask (pure causal; handled analytically)
    const float* wq     = (const float*)d_in[4];
    const float* wk     = (const float*)d_in[5];
    const float* wv     = (const float*)d_in[6];
    const float* wo     = (const float*)d_in[7];
    const float* qnw    = (const float*)d_in[8];
    const float* knw    = (const float*)d_in[9];
    float* out = (float*)d_out;

    char* ws = (char*)d_ws;
    u16* hidden_bf = (u16*)ws;                          // [0,8M)
    u16* wqkvT     = (u16*)(ws + ((size_t)8  << 20));   // [8,20M) -> later attn_bf
    u16* attn_bf   = (u16*)(ws + ((size_t)8  << 20));
    u16* qkv_bf    = (u16*)(ws + ((size_t)20 << 20));   // [20,32M)
    u16* v_bfT     = (u16*)(ws + ((size_t)32 << 20));   // [32,34M)
    u16* woT       = (u16*)(ws + ((size_t)34 << 20));   // [34,42M)

    // hidden -> bf16, wq|wk|wv pack-transpose, wo transpose
    preproc1<<<4608, 256, 0, stream>>>(hidden, wq, wk, wv, wo,
                                       hidden_bf, wqkvT, woT);

    // fused QKV projection: [2048,2048] @ [2048,3072] -> bf16 [2048,3072]
    // BM=128, BN=64 -> 768 blocks (3/CU); XCD owns 2 m-panels x all n
    gemm_bt<128, 64, true><<<768, 256, 0, stream>>>(hidden_bf, wqkvT, qkv_bf,
                                                    2048, 3072, 2048);

    // RMSNorm + RoPE for Q and K (in place, Q pre-scaled) + V transpose
    rmsnorm_rope_vt<<<2304, 256, 0, stream>>>(qkv_bf, qnw, knw, cosb, sinb, v_bfT);

    // attention -> attn_bf: 32-row strip pairs, 2 waves/block,
    // grid 1024 = 4 blocks/CU (36KB LDS)
    attn_pair<<<1024, 128, 0, stream>>>(qkv_bf, v_bfT, attn_bf);

    // output projection: [2048,2048] @ woT^T -> fp32 out
    // BM=64, BN=64 -> 1024 blocks (4/CU); XCD owns 4 m-panels x all n
    gemm_bt<64, 64, false><<<1024, 256, 0, stream>>>(attn_bf, woT, out,
                                                     2048, 2048, 2048);
}

// Round 26
// 116.558 us; speedup vs baseline: 1.0196x; 1.0196x over previous
//
#include <hip/hip_runtime.h>

#define B_    2
#define S_    1024
#define NH_   32
#define NKV_  8
#define T_    (B_*S_)

typedef unsigned short u16;
typedef unsigned int u32;
typedef __attribute__((ext_vector_type(8))) short bf16x8;
typedef __attribute__((ext_vector_type(4))) float f32x4;

__device__ __forceinline__ float bf2f(u16 u) {
    union { float f; unsigned int i; } c; c.i = ((unsigned int)u) << 16; return c.f;
}
// pack two f32 -> 2xbf16 (lo in low16), RNE
__device__ __forceinline__ u32 cvtpk(float lo, float hi) {
    u32 r;
    asm("v_cvt_pk_bf16_f32 %0, %1, %2" : "=v"(r) : "v"(lo), "v"(hi));
    return r;
}
// single f32 -> bf16 via cvt_pk (1 VALU op, RNE)
__device__ __forceinline__ u16 f2bf(float f) {
    return (u16)cvtpk(f, 0.f);
}

// async global->LDS, 16B per lane; LDS dest = wave-uniform base + lane*16 (linear)
__device__ __forceinline__ void gld_lds16(const void* g, void* s) {
    __builtin_amdgcn_global_load_lds(
        (const __attribute__((address_space(1))) void*)g,
        (__attribute__((address_space(3))) void*)s,
        16, 0, 0);
}

// ------------------------------------------------------------------
// preproc1: [0,2048) hidden f32->bf16; [2048,3584) wqkv pack-transpose;
//           [3584,4608) wo transpose -> woT bf16 [2048][2048]
// Transpose path vectorized (G13): float4 reads, uint2 bf16 stores.
// ------------------------------------------------------------------
__global__ __launch_bounds__(256) void preproc1(
    const float* __restrict__ hidden, const float* __restrict__ wq,
    const float* __restrict__ wk, const float* __restrict__ wv,
    const float* __restrict__ wo,
    u16* __restrict__ hidden_bf, u16* __restrict__ wqkvT, u16* __restrict__ woT)
{
    __shared__ float t[64][65];
    const int bid = blockIdx.x, tid = threadIdx.x;
    if (bid < 2048) {
        int i = (bid * 256 + tid) * 8;
        float4 v0 = *reinterpret_cast<const float4*>(&hidden[i]);
        float4 v1 = *reinterpret_cast<const float4*>(&hidden[i + 4]);
        u32 ow[4] = { cvtpk(v0.x, v0.y), cvtpk(v0.z, v0.w),
                      cvtpk(v1.x, v1.y), cvtpk(v1.z, v1.w) };
        *reinterpret_cast<uint4*>(&hidden_bf[i]) = *reinterpret_cast<uint4*>(ow);
        return;
    }
    const float* src; int scol, sN, n0, k0;
    u16* dst; int dK;
    if (bid < 3584) {
        const int tt = bid - 2048;
        n0 = (tt % 48) * 64; k0 = (tt / 48) * 64;
        if (n0 < 2048)      { src = wq; scol = n0;        sN = 2048; }
        else if (n0 < 2560) { src = wk; scol = n0 - 2048; sN = 512;  }
        else                { src = wv; scol = n0 - 2560; sN = 512;  }
        dst = wqkvT; dK = 2048;
    } else {
        const int tt = bid - 3584;
        n0 = (tt % 32) * 64; k0 = (tt / 32) * 64;
        src = wo; scol = n0; sN = 2048;
        dst = woT; dK = 2048;
    }
    #pragma unroll
    for (int i = 0; i < 4; ++i) {
        int e = i * 256 + tid, r = e >> 4, c4 = (e & 15) * 4;
        float4 v = *reinterpret_cast<const float4*>(
            &src[(size_t)(k0 + r) * sN + scol + c4]);
        t[r][c4 + 0] = v.x;
        t[r][c4 + 1] = v.y;
        t[r][c4 + 2] = v.z;
        t[r][c4 + 3] = v.w;
    }
    __syncthreads();
    #pragma unroll
    for (int i = 0; i < 4; ++i) {
        int e = i * 256 + tid, rr = e >> 4, cc4 = (e & 15) * 4;
        u32 ow[2] = { cvtpk(t[cc4][rr], t[cc4 + 1][rr]),
                      cvtpk(t[cc4 + 2][rr], t[cc4 + 3][rr]) };
        *reinterpret_cast<uint2*>(&dst[(size_t)(n0 + rr) * dK + k0 + cc4])
            = *reinterpret_cast<uint2*>(ow);
    }
}

// ------------------------------------------------------------------
// bf16 MFMA GEMM, B^T input. C[M,N] = A[M,K] @ Bt[N,K]^T
// BM x BN tile (templated), BK=64, 4 waves (2x2), wave-tile
// (BM/2)x(BN/2), T2 XOR-swizzled LDS, double-buffered counted-vmcnt
// staging. XCD mapping: each XCD owns MB/8 contiguous m-panels and
// ALL n-columns (grid/8 blocks per XCD are exactly co-resident).
// ------------------------------------------------------------------
template<int BM, int BN, bool OUT_BF16>
__global__ __launch_bounds__(256) void gemm_bt(
    const u16* __restrict__ A, const u16* __restrict__ Bt,
    void* __restrict__ Cv, int M, int N, int K)
{
    constexpr int FM  = BM / 32;        // A frags per wave
    constexpr int FN  = BN / 32;        // B frags per wave
    constexpr int ACH = BM / 32;        // A chunks staged per wave
    constexpr int BCH = BN / 32;        // B chunks staged per wave
    __shared__ u16 As[2][BM * 64];
    __shared__ u16 Bs[2][BN * 64];
    const int MB = M / BM;
    const int mpx = MB >> 3;                          // m-panels per XCD
    const int xcd = blockIdx.x & 7, lid = blockIdx.x >> 3;
    const int bm = (xcd * mpx + (lid % mpx)) * BM;
    const int bn = (lid / mpx) * BN;
    const int tid = threadIdx.x;
    const int w = tid >> 6, lane = tid & 63;
    const int wr = w >> 1, wc = w & 1;
    const int l15 = lane & 15, lg = lane >> 4;
    const int srow = lane >> 3;                       // 0..7
    const int scolsw = (lane & 7) ^ srow;             // swizzled source 16B-chunk

    f32x4 acc[FM][FN] = {};
    const int nk = K >> 6;

#define GSTAGE(ks, bb) do {                                                    \
    const int kofs = (ks) * 64;                                                \
    _Pragma("unroll")                                                          \
    for (int i_ = 0; i_ < ACH; ++i_) {                                         \
        int chunk_ = w * ACH + i_;                                             \
        int row_ = chunk_ * 8 + srow;                                          \
        gld_lds16(&A[(size_t)(bm + row_) * K + kofs + scolsw * 8],             \
                  &As[bb][chunk_ * 512]);                                      \
    }                                                                          \
    _Pragma("unroll")                                                          \
    for (int j_ = 0; j_ < BCH; ++j_) {                                         \
        int chunk_ = w * BCH + j_;                                             \
        int row_ = chunk_ * 8 + srow;                                          \
        gld_lds16(&Bt[(size_t)(bn + row_) * K + kofs + scolsw * 8],            \
                  &Bs[bb][chunk_ * 512]);                                      \
    } } while (0)

    GSTAGE(0, 0);
    for (int ks = 0; ks < nk; ++ks) {
        const int cur = ks & 1;
        if (ks + 1 < nk) {
            GSTAGE(ks + 1, cur ^ 1);
            if (ACH + BCH == 6)      { asm volatile("s_waitcnt vmcnt(6)" ::: "memory"); }
            else if (ACH + BCH == 4) { asm volatile("s_waitcnt vmcnt(4)" ::: "memory"); }
            else                     { asm volatile("s_waitcnt vmcnt(0)" ::: "memory"); }
        } else {
            asm volatile("s_waitcnt vmcnt(0)" ::: "memory");
        }
        __builtin_amdgcn_s_barrier();
        __builtin_amdgcn_sched_barrier(0);   // keep ds_reads below barrier

        #pragma unroll
        for (int kk = 0; kk < 2; ++kk) {
            const int phys = ((kk * 4 + lg) ^ (l15 & 7)) * 8;
            bf16x8 a[FM], b[FN];
            #pragma unroll
            for (int m = 0; m < FM; ++m)
                a[m] = *reinterpret_cast<const bf16x8*>(
                    &As[cur][(wr * (BM / 2) + m * 16 + l15) * 64 + phys]);
            #pragma unroll
            for (int n = 0; n < FN; ++n)
                b[n] = *reinterpret_cast<const bf16x8*>(
                    &Bs[cur][(wc * (BN / 2) + n * 16 + l15) * 64 + phys]);
            #pragma unroll
            for (int m = 0; m < FM; ++m)
                #pragma unroll
                for (int n = 0; n < FN; ++n)
                    acc[m][n] = __builtin_amdgcn_mfma_f32_16x16x32_bf16(
                        a[m], b[n], acc[m][n], 0, 0, 0);
        }
        __builtin_amdgcn_s_barrier();   // protect buffer reuse next iter
    }
#undef GSTAGE

    const int orow0 = bm + wr * (BM / 2), ocol0 = bn + wc * (BN / 2);
    #pragma unroll
    for (int m = 0; m < FM; ++m)
        #pragma unroll
        for (int n = 0; n < FN; ++n)
            #pragma unroll
            for (int r = 0; r < 4; ++r) {
                int row = orow0 + m * 16 + lg * 4 + r;
                int col = ocol0 + n * 16 + l15;
                float v = acc[m][n][r];
                if (OUT_BF16)
                    ((u16*)Cv)[(size_t)row * N + col] = f2bf(v);
                else
                    ((float*)Cv)[(size_t)row * N + col] = v;
            }
}

// ------------------------------------------------------------------
// Merged RMSNorm+RoPE (blocks [0,2048), token per block) and
// V transpose (blocks [2048,2304)) -> vT [(b*8+kvh)*64+d][1024]
// Q rows are additionally scaled by SC = 0.125*log2(e) so the attn
// kernel's softmax can use exp2 on the raw QK^T product directly.
// ------------------------------------------------------------------
template<int DIM>
__device__ __forceinline__ void rms_rope_row(
    u16* base, const float* __restrict__ w,
    const float* __restrict__ cs, const float* __restrict__ sn,
    float* row, float* red, int tid, float osc)
{
    float ss = 0.f;
    for (int i0 = tid * 8; i0 < DIM; i0 += 2048) {
        uint4 u = *reinterpret_cast<const uint4*>(&base[i0]);
        const u16* us = reinterpret_cast<const u16*>(&u);
        #pragma unroll
        for (int j = 0; j < 8; ++j) { float f = bf2f(us[j]); row[i0 + j] = f; ss += f * f; }
    }
    #pragma unroll
    for (int off = 1; off < 64; off <<= 1) ss += __shfl_xor(ss, off);
    if ((tid & 63) == 0) red[tid >> 6] = ss;
    __syncthreads();
    const float rstd = rsqrtf((red[0] + red[1] + red[2] + red[3]) * (1.0f / DIM) + 1e-6f);

    for (int i0 = tid * 8; i0 < DIM; i0 += 2048) {
        float ov[8];
        #pragma unroll
        for (int j = 0; j < 8; ++j) {
            int i = i0 + j, dh = i & 63, bb = i & ~63;
            int oi = (dh < 32) ? bb + dh + 32 : bb + dh - 32;
            float y     = row[i]  * rstd * w[i];
            float other = row[oi] * rstd * w[oi];
            if (dh < 32) other = -other;
            ov[j] = (y * cs[dh] + other * sn[dh]) * osc;
        }
        u32 ow[4] = { cvtpk(ov[0], ov[1]), cvtpk(ov[2], ov[3]),
                      cvtpk(ov[4], ov[5]), cvtpk(ov[6], ov[7]) };
        *reinterpret_cast<uint4*>(&base[i0]) = *reinterpret_cast<uint4*>(ow);
    }
}

__global__ __launch_bounds__(256) void rmsnorm_rope_vt(
    u16* __restrict__ x, const float* __restrict__ qnw, const float* __restrict__ knw,
    const float* __restrict__ cosb, const float* __restrict__ sinb,
    u16* __restrict__ vT)
{
    __shared__ float smem[2304];          // 9216 B, aliased
    const int bid = blockIdx.x, tid = threadIdx.x;
    if (bid < 2048) {
        const int t = bid;
        float* row = smem;
        float* red = smem + 2048;
        const float* cs = cosb + (size_t)t * 64;
        const float* sn = sinb + (size_t)t * 64;
        // Q: scaled by 0.125*log2(e) (softmax scale folded in)
        rms_rope_row<2048>(x + (size_t)t * 3072,        qnw, cs, sn, row, red, tid,
                           0.18033688f);
        __syncthreads();
        rms_rope_row<512 >(x + (size_t)t * 3072 + 2048, knw, cs, sn, row, red, tid,
                           1.0f);
        return;
    }
    // V transpose
    u16 (*tu)[72] = reinterpret_cast<u16(*)[72]>(smem);
    const int bid2 = bid - 2048;
    const int hd = bid2 % 16;              // b*8 + kvh
    const int s0 = (bid2 / 16) * 64;
    const int b = hd >> 3, kvh = hd & 7;
    #pragma unroll
    for (int i = 0; i < 2; ++i) {
        int chunk = i * 256 + tid;
        int r = chunk >> 3, c8 = (chunk & 7) * 8;
        uint4 u = *reinterpret_cast<const uint4*>(
            &x[(size_t)(b * 1024 + s0 + r) * 3072 + 2560 + kvh * 64 + c8]);
        *reinterpret_cast<uint4*>(&tu[r][c8]) = u;
    }
    __syncthreads();
    #pragma unroll
    for (int i = 0; i < 2; ++i) {
        int chunk = i * 256 + tid;
        int d = chunk >> 3, c8 = (chunk & 7) * 8;
        u16 o[8];
        #pragma unroll
        for (int j = 0; j < 8; ++j) o[j] = tu[c8 + j][d];
        *reinterpret_cast<uint4*>(&vT[((size_t)(hd * 64 + d)) * 1024 + s0 + c8])
            = *reinterpret_cast<uint4*>(o);
    }
}

// ------------------------------------------------------------------
// MFMA flash attention (r24 best config): max-free softmax (scale
// pre-folded into Q), diagonal-only masking, cvt_pk packing,
// pair-tiled strips p & 15-p (17 uniform steps), K/V triple-buffered
// (one barrier/step), single load-bearing sched_barrier, grid 512.
// ------------------------------------------------------------------
__global__ __launch_bounds__(256) void attn_tb(
    const u16* __restrict__ qkv,  // [2048][3072]
    const u16* __restrict__ vT,   // [16*64][1024]
    u16* __restrict__ ob)         // [2048][2048]
{
    __shared__ u16 Ks[3][64 * 64];
    __shared__ u16 Vs[3][64 * 64];
    __shared__ u16 Ps[4][16 * 64];

    const int bid = blockIdx.x;
    const int L   = (bid & 7) * 64 + (bid >> 3);   // XCD-chunked, bijective
    const int g5  = L >> 5;                        // b*8 + kvh
    const int rem = L & 31;
    const int ha  = rem & 3;
    const int p   = rem >> 2;                      // pair index 0..7
    const int b = g5 >> 3, kvh = g5 & 7;
    const int h = kvh * 4 + ha;
    const int qtA = p, qtB = 15 - p;

    const int tid = threadIdx.x, w = tid >> 6, lane = tid & 63;
    const int l15 = lane & 15, lg = lane >> 4;
    const int srow = lane >> 3;
    const int scolsw = (lane & 7) ^ srow;

    // Q fragments for both tiles (q-row = l15 of wave's 16)
    bf16x8 qfA[2], qfB[2];
    {
        const size_t rA = (size_t)(b * 1024 + qtA * 64 + w * 16 + l15);
        const size_t rB = (size_t)(b * 1024 + qtB * 64 + w * 16 + l15);
        #pragma unroll
        for (int kk = 0; kk < 2; ++kk) {
            qfA[kk] = *reinterpret_cast<const bf16x8*>(
                &qkv[rA * 3072 + h * 64 + kk * 32 + lg * 8]);
            qfB[kk] = *reinterpret_cast<const bf16x8*>(
                &qkv[rB * 3072 + h * 64 + kk * 32 + lg * 8]);
        }
    }
    asm volatile("s_waitcnt vmcnt(0)" ::: "memory");  // clean vmcnt for pipeline

    float lrA = 0.f, lrB = 0.f;          // per-lane partial row sums
    f32x4 oaccA[4] = {}, oaccB[4] = {};

    const u16* kbase = qkv + 2048 + kvh * 64;
    const u16* vbase = vT + (size_t)(g5 * 64) * 1024;
    const int qgA = qtA * 64 + w * 16 + l15;
    const int qgB = qtB * 64 + w * 16 + l15;

#define ASTAGE(kt, bb) do {                                                    \
    _Pragma("unroll")                                                          \
    for (int i_ = 0; i_ < 2; ++i_) {                                           \
        int chunk_ = w * 2 + i_;                                               \
        int row_ = chunk_ * 8 + srow;                                          \
        gld_lds16(&kbase[(size_t)(b * 1024 + (kt) * 64 + row_) * 3072          \
                         + scolsw * 8], &Ks[bb][chunk_ * 512]);                \
        gld_lds16(&vbase[(size_t)row_ * 1024 + (kt) * 64 + scolsw * 8],        \
                  &Vs[bb][chunk_ * 512]);                                      \
    } } while (0)

    // one tile-step: max-free online accumulation; scale pre-folded in Q.
    auto step = [&](int kt, int cur, const bf16x8 (&qf)[2],
                    float& lr, f32x4 (&oacc)[4], int qg, bool dz) {
        // swapped QK^T: D[key][q], lane holds q=l15, keys m*16+lg*4+r
        f32x4 sacc[4] = {};
        #pragma unroll
        for (int kk = 0; kk < 2; ++kk) {
            const int phys = ((kk * 4 + lg) ^ (l15 & 7)) * 8;
            #pragma unroll
            for (int m = 0; m < 4; ++m) {
                bf16x8 kf = *reinterpret_cast<const bf16x8*>(
                    &Ks[cur][(m * 16 + l15) * 64 + phys]);
                sacc[m] = __builtin_amdgcn_mfma_f32_16x16x32_bf16(
                    kf, qf[kk], sacc[m], 0, 0, 0);
            }
        }

        // max-free: P = exp2(S); mask only on the diagonal step (wave-
        // uniform dz branch -> 15/17 steps skip the cmp/select entirely)
        float pv[4][4];
        if (dz) {
            #pragma unroll
            for (int m = 0; m < 4; ++m)
                #pragma unroll
                for (int r = 0; r < 4; ++r) {
                    float v = sacc[m][r];
                    if (kt * 64 + m * 16 + lg * 4 + r > qg) v = -1e30f;
                    pv[m][r] = exp2f(v);
                }
        } else {
            #pragma unroll
            for (int m = 0; m < 4; ++m)
                #pragma unroll
                for (int r = 0; r < 4; ++r)
                    pv[m][r] = exp2f(sacc[m][r]);
        }
        float ls = 0.f;
        #pragma unroll
        for (int m = 0; m < 4; ++m) {
            ls += (pv[m][0] + pv[m][1]) + (pv[m][2] + pv[m][3]);
            u32 pkw[2] = { cvtpk(pv[m][0], pv[m][1]),
                           cvtpk(pv[m][2], pv[m][3]) };
            const int keyc = m * 16 + lg * 4;
            const int phys = (keyc >> 3) ^ (l15 & 7);
            *reinterpret_cast<uint2*>(&Ps[w][l15 * 64 + phys * 8 + (keyc & 7)])
                = *reinterpret_cast<const uint2*>(pkw);
        }
        lr += ls;                         // per-lane partial; reduce at end

        // PV: O[q][d] += P[q][key] * V[key][d]
        // (Ps RAW handled by compiler's counted lgkm waits)
        #pragma unroll
        for (int kk = 0; kk < 2; ++kk) {
            const int phys = ((kk * 4 + lg) ^ (l15 & 7)) * 8;
            bf16x8 pf = *reinterpret_cast<const bf16x8*>(
                &Ps[w][l15 * 64 + phys]);
            #pragma unroll
            for (int d = 0; d < 4; ++d) {
                bf16x8 vf = *reinterpret_cast<const bf16x8*>(
                    &Vs[cur][(d * 16 + l15) * 64 + phys]);
                oacc[d] = __builtin_amdgcn_mfma_f32_16x16x32_bf16(
                    pf, vf, oacc[d], 0, 0, 0);
            }
        }
    };

    // 17-step schedule, ONE barrier per step (triple-buffered K/V):
    // s<=p -> tile A (kt=s), else tile B (kt=s-p-1)
    ASTAGE(0, 0);
    for (int s = 0; s <= 16; ++s) {
        const int cur = s % 3;
        if (s < 16) {
            const int ktn = (s + 1 <= p) ? (s + 1) : (s - p);
            ASTAGE(ktn, (s + 1) % 3);
            asm volatile("s_waitcnt vmcnt(4)" ::: "memory");
        } else {
            asm volatile("s_waitcnt vmcnt(0)" ::: "memory");
        }
        __builtin_amdgcn_s_barrier();
        __builtin_amdgcn_sched_barrier(0);   // keep ds_reads below barrier

        if (s <= p) step(s,         cur, qfA, lrA, oaccA, qgA, s == p);
        else        step(s - p - 1, cur, qfB, lrB, oaccB, qgB, s == 16);
        // no trailing barrier: stage(s+1) at next iter writes (s+1)%3,
        // disjoint from any buffer still being read.
    }
#undef ASTAGE

    // epilogues: reduce l across the 4 lane-groups once, then normalize.
    #pragma unroll
    for (int tt = 0; tt < 2; ++tt) {
        const int qt = tt ? qtB : qtA;
        float lsum = tt ? lrB : lrA;
        lsum += __shfl_xor(lsum, 16);
        lsum += __shfl_xor(lsum, 32);
        f32x4* oacc = tt ? oaccB : oaccA;
        float linv[4];
        #pragma unroll
        for (int r = 0; r < 4; ++r) {
            float lv = __shfl(lsum, (lane & 48) + ((lane >> 4) & 3) * 4 + r);
            linv[r] = 1.f / lv;
        }
        #pragma unroll
        for (int d = 0; d < 4; ++d)
            #pragma unroll
            for (int r = 0; r < 4; ++r)
                ob[(size_t)(b * 1024 + qt * 64 + w * 16 + lg * 4 + r) * 2048
                   + h * 64 + d * 16 + l15] = f2bf(oacc[d][r] * linv[r]);
    }
}

// ------------------------------------------------------------------
extern "C" void kernel_launch(void* const* d_in, const int* in_sizes, int n_in,
                              void* d_out, int out_size, void* d_ws, size_t ws_size,
                              hipStream_t stream)
{
    const float* hidden = (const float*)d_in[0];
    const float* cosb   = (const float*)d_in[1];
    const float* sinb   = (const float*)d_in[2];
    // d_in[3] = attention_mask (pure causal; handled analytically)
    const float* wq     = (const float*)d_in[4];
    const float* wk     = (const float*)d_in[5];
    const float* wv     = (const float*)d_in[6];
    const float* wo     = (const float*)d_in[7];
    const float* qnw    = (const float*)d_in[8];
    const float* knw    = (const float*)d_in[9];
    float* out = (float*)d_out;

    char* ws = (char*)d_ws;
    u16* hidden_bf = (u16*)ws;                          // [0,8M)
    u16* wqkvT     = (u16*)(ws + ((size_t)8  << 20));   // [8,20M) -> later attn_bf
    u16* attn_bf   = (u16*)(ws + ((size_t)8  << 20));
    u16* qkv_bf    = (u16*)(ws + ((size_t)20 << 20));   // [20,32M)
    u16* v_bfT     = (u16*)(ws + ((size_t)32 << 20));   // [32,34M)
    u16* woT       = (u16*)(ws + ((size_t)34 << 20));   // [34,42M)

    // hidden -> bf16, wq|wk|wv pack-transpose, wo transpose
    preproc1<<<4608, 256, 0, stream>>>(hidden, wq, wk, wv, wo,
                                       hidden_bf, wqkvT, woT);

    // fused QKV projection: [2048,2048] @ [2048,3072] -> bf16 [2048,3072]
    // BM=128, BN=64 -> 768 blocks (3/CU); XCD owns 2 m-panels x all n
    gemm_bt<128, 64, true><<<768, 256, 0, stream>>>(hidden_bf, wqkvT, qkv_bf,
                                                    2048, 3072, 2048);

    // RMSNorm + RoPE for Q and K (in place, Q pre-scaled) + V transpose
    rmsnorm_rope_vt<<<2304, 256, 0, stream>>>(qkv_bf, qnw, knw, cosb, sinb, v_bfT);

    // attention -> attn_bf (aliases wqkvT region, free after QKV GEMM)
    attn_tb<<<512, 256, 0, stream>>>(qkv_bf, v_bfT, attn_bf);

    // output projection: [2048,2048] @ woT^T -> fp32 out
    // BM=64, BN=64 -> 1024 blocks (4/CU); XCD owns 4 m-panels x all n
    gemm_bt<64, 64, false><<<1024, 256, 0, stream>>>(attn_bf, woT, out,
                                                     2048, 2048, 2048);
}